// Round 6
// baseline (194.634 us; speedup 1.0000x reference)
//
#include <hip/hip_runtime.h>
#include <hip/hip_fp8.h>

// HardNetLoss: a = x[:8192], p = x[8192:], d_ij = sqrt((1 - a_i·p_j + 1e-6)*2)
// pos_i = d_ii ; neg_i = min(min_{j!=i} d_ji, min_{j!=i} d_ij)
// out = mean(relu(1 - neg + pos))
//
// R16: R15 (no atomics) == R12 (atomics) == R10 (dup feed) at ~92us total:
// dist ~31us in all three => bottleneck is neither feed nor atomics but
// occupancy/latency: 64KB LDS + 128 VGPR + bounds(256,2) = 2 waves/SIMD,
// serial per-block chain, no pipe >22% busy (R14 counters). R16: 128x128
// tile, grid 4096, LDS 32KB, acc 64 VGPR -> bounds(256,4) = 4 blocks/CU
// (4 waves/SIMD, 2x TLP). Same total feed (262MB). Epilogue: no barriers,
// no LDS, no atomics -- col via 1 shuffle, row via 5-step shfl_xor
// butterfly, per-wave partials as plain coalesced stores (8MB), reduced
// by finalize1. dist has ONE barrier total (post-stage drain).
// 32x32 C/D layout: col = lane&31, row = (reg&3)+8*(reg>>2)+4*(lane>>5).

#define CNT    8192
#define KDIM   256
#define BIGF   3.0e38f
#define SCALE1 0x7F7F7F7F            // 4x e8m0 bytes, each = 2^0

typedef float f32x4  __attribute__((ext_vector_type(4)));
typedef float f32x16 __attribute__((ext_vector_type(16)));
typedef int   v8i    __attribute__((ext_vector_type(8)));

union frag8 { uint4 q[2]; v8i v; };

__device__ __forceinline__ unsigned short f2bf(float f) {
    unsigned u = __float_as_uint(f);
    u += 0x7FFFu + ((u >> 16) & 1u);          // round-to-nearest-even
    return (unsigned short)(u >> 16);
}

__device__ __forceinline__ unsigned cvt4_fp8(float a, float b, float c, float d) {
#if __has_builtin(__builtin_amdgcn_cvt_pk_fp8_f32)
    unsigned v = __builtin_amdgcn_cvt_pk_fp8_f32(a, b, 0, false);
    v = __builtin_amdgcn_cvt_pk_fp8_f32(c, d, v, true);
    return v;
#else
    return (unsigned)__hip_fp8_e4m3(a).__x |
           ((unsigned)__hip_fp8_e4m3(b).__x << 8) |
           ((unsigned)__hip_fp8_e4m3(c).__x << 16) |
           ((unsigned)__hip_fp8_e4m3(d).__x << 24);
#endif
}

// ---------------- fast path ----------------

// x fp32 [16384][256] -> xb fp8, MX-fragment-packed. Chunk (rg32, kc64) is
// 2KB: half h holds j 0..15 (h=0) / 16..31 (h=1) of each lane's 32-k block;
// lane = (row%32) + 32*((col%64)/32). Thread T writes 16B at xb + T*16.
__global__ __launch_bounds__(256) void convert_mx_kernel(
    const float* __restrict__ x, unsigned char* __restrict__ xb)
{
    int T    = blockIdx.x * 256 + threadIdx.x;   // 262144 threads
    int lane = T & 63;
    int h    = (T >> 6) & 1;
    int c    = T >> 7;                           // chunk 0..2047
    int kc64 = c & 3;
    int rg   = c >> 2;                           // 32-row group
    int row  = rg * 32 + (lane & 31);
    int col0 = kc64 * 64 + (lane >> 5) * 32 + h * 16;
    const float* src = x + (size_t)row * KDIM + col0;
    float4 u0 = *(const float4*)(src);
    float4 u1 = *(const float4*)(src + 4);
    float4 u2 = *(const float4*)(src + 8);
    float4 u3 = *(const float4*)(src + 12);
    uint4 w;
    w.x = cvt4_fp8(u0.x, u0.y, u0.z, u0.w);
    w.y = cvt4_fp8(u1.x, u1.y, u1.z, u1.w);
    w.z = cvt4_fp8(u2.x, u2.y, u2.z, u2.w);
    w.w = cvt4_fp8(u3.x, u3.y, u3.z, u3.w);
    *(uint4*)(xb + (size_t)T * 16) = w;
}

// block tile 128(m) x 128(n); 4 waves 2x2; wave tile 64x64 of 32x32x64 MFMA.
__global__ __launch_bounds__(256, 4) void dist16_kernel(
    const unsigned char* __restrict__ Ab_, const unsigned char* __restrict__ Pb_,
    float* __restrict__ rowpart, float* __restrict__ colpart,
    float* __restrict__ g_pos)
{
    __shared__ char smem[32768];                 // P slice (16 chunks x 2KB)

    const char* Ab = (const char*)Ab_;
    const char* Pb = (const char*)Pb_;

    const int tid  = threadIdx.x;
    // bijective XCD swizzle: 4096 = 8 xcds x 512; each XCD owns 8 bm2 x all bn2
    const int l    = blockIdx.x;
    const int xcd  = l & 7;
    const int i    = l >> 3;                     // 0..511
    const int bm2  = xcd * 8 + (i & 7);          // 0..63
    const int bn2  = i >> 3;                     // 0..63

    const int wave = tid >> 6;
    const int lane = tid & 63;
    const int l31  = lane & 31;
    const int kh   = lane >> 5;                  // k-half / C-row-half selector
    const int wm   = wave >> 1;                  // 0..1 : m half (64 rows)
    const int wn   = wave & 1;                   // 0..1 : n half (64 cols)

    // stage P slice: rg bn2*4+{0..3} x 4 kc = 16 chunks x 2KB = 32KB.
    // LDS chunk cc = kc*4 + rgl. 32 half-chunks / 4 waves = 8 per wave.
    // global_load_lds: dest wave-uniform base, HW adds lane*16 (packed match).
    #pragma unroll
    for (int t = 0; t < 8; t++) {
        const int o   = wave * 8 + t;            // 0..31
        const int cc  = o >> 1;                  // 0..15 : kcs*4 + rgl
        const int h   = o & 1;
        const int rgl = cc & 3;
        const int kcs = cc >> 2;
        const char* src = Pb + (((size_t)(bn2 * 4 + rgl)) << 13)
                             + kcs * 2048 + h * 1024 + lane * 16;
        __builtin_amdgcn_global_load_lds(
            (const __attribute__((address_space(1))) void*)src,
            (__attribute__((address_space(3))) void*)(smem + cc * 2048 + h * 1024),
            16, 0, 0);
    }
    __syncthreads();                             // the one barrier (DMA drain)

    f32x16 acc[2][2];
    #pragma unroll
    for (int a = 0; a < 2; a++)
        #pragma unroll
        for (int b = 0; b < 2; b++)
            #pragma unroll
            for (int r = 0; r < 16; r++)
                acc[a][b][r] = 0.f;

    const char* Abase = Ab + lane * 16;
    size_t a_off[2];
    #pragma unroll
    for (int mi = 0; mi < 2; mi++)
        a_off[mi] = (size_t)(bm2 * 4 + wm * 2 + mi) << 13;   // rg32 * 8192

    // K-loop: 4 steps of K=64, no barriers. A from global (compiler
    // pipelines under the 128-VGPR cap), B from LDS (lane-linear b128).
    #pragma unroll
    for (int kc = 0; kc < 4; kc++) {
        frag8 fa[2], fb[2];
        #pragma unroll
        for (int mi = 0; mi < 2; mi++) {
            fa[mi].q[0] = *(const uint4*)(Abase + a_off[mi] + kc * 2048);
            fa[mi].q[1] = *(const uint4*)(Abase + a_off[mi] + kc * 2048 + 1024);
        }
        #pragma unroll
        for (int ni = 0; ni < 2; ni++) {
            const char* p = smem + (kc * 4 + wn * 2 + ni) * 2048 + lane * 16;
            fb[ni].q[0] = *(const uint4*)(p);
            fb[ni].q[1] = *(const uint4*)(p + 1024);
        }
        #pragma unroll
        for (int mi = 0; mi < 2; mi++)
            #pragma unroll
            for (int ni = 0; ni < 2; ni++)
                acc[mi][ni] = __builtin_amdgcn_mfma_scale_f32_32x32x64_f8f6f4(
                    fa[mi].v, fb[ni].v, acc[mi][ni],
                    0, 0,                 // cbsz = fp8 e4m3, blgp = fp8 e4m3
                    0, SCALE1,            // scale_a opsel, scale_a
                    0, SCALE1);           // scale_b opsel, scale_b
    }

    // ---- epilogue (no barriers, no LDS, no atomics).
    // C/D: col = l31, row = (reg&3) + 8*(reg>>2) + 4*kh.
    // local row rl = wm*64 + mi*32 + rowf(reg)   (0..127)
    // local col cl = wn*64 + ni*32 + l31         (0..127)

    if (bm2 == bn2) {                            // diagonal block
        #pragma unroll
        for (int mi = 0; mi < 2; mi++)
            #pragma unroll
            for (int ni = 0; ni < 2; ni++)
                #pragma unroll
                for (int reg = 0; reg < 16; reg++) {
                    int rl = wm * 64 + mi * 32 + (reg & 3) + 8 * (reg >> 2) + 4 * kh;
                    int cl = wn * 64 + ni * 32 + l31;
                    if (cl == rl) {
                        g_pos[bm2 * 128 + rl] = (1.0f - acc[mi][ni][reg] + 1e-6f) * 2.0f;
                        acc[mi][ni][reg] = -BIGF;
                    }
                }
    }

    // col-direction (min over this wave's 64 rows => max s): in-lane fold
    // over mi,reg + 1 kh-shuffle; kh==0 lanes store wave partial (coalesced).
    #pragma unroll
    for (int ni = 0; ni < 2; ni++) {
        float v = -BIGF;
        #pragma unroll
        for (int mi = 0; mi < 2; mi++)
            #pragma unroll
            for (int reg = 0; reg < 16; reg++)
                v = fmaxf(v, acc[mi][ni][reg]);
        v = fmaxf(v, __shfl_xor(v, 32, 64));
        if (kh == 0) {
            float tt = fmaxf((1.0f - v + 1e-6f) * 2.0f, 0.0f);
            colpart[(size_t)(bm2 * 2 + wm) * CNT
                    + bn2 * 128 + wn * 64 + ni * 32 + l31] = tt;
        }
    }

    // row-direction (min over this wave's 64 cols): in-lane ni-fold, then
    // 5-step shfl_xor butterfly within the kh-half; l31==0 lane stores.
    #pragma unroll
    for (int mi = 0; mi < 2; mi++)
        #pragma unroll
        for (int reg = 0; reg < 16; reg++) {
            float v = fmaxf(acc[mi][0][reg], acc[mi][1][reg]);
            v = fmaxf(v, __shfl_xor(v, 1, 64));
            v = fmaxf(v, __shfl_xor(v, 2, 64));
            v = fmaxf(v, __shfl_xor(v, 4, 64));
            v = fmaxf(v, __shfl_xor(v, 8, 64));
            v = fmaxf(v, __shfl_xor(v, 16, 64));
            if (l31 == 0) {
                int rl = wm * 64 + mi * 32 + (reg & 3) + 8 * (reg >> 2) + 4 * kh;
                float tt = fmaxf((1.0f - v + 1e-6f) * 2.0f, 0.0f);
                rowpart[(size_t)(bn2 * 2 + wn) * CNT + bm2 * 128 + rl] = tt;
            }
        }
}

// finalize1: 32 blocks x 256 = 8192 threads, one per element. Reduces 128
// rowpart + 128 colpart slabs (coalesced: consecutive threads -> consecutive
// i), computes the loss term, stores one partial sum per block.
__global__ __launch_bounds__(256) void finalize1_kernel(
    const float* __restrict__ rowpart, const float* __restrict__ colpart,
    const float* __restrict__ post, float* __restrict__ psum)
{
    const int i = blockIdx.x * 256 + threadIdx.x;
    float rv = BIGF, cv = BIGF;
    #pragma unroll 8
    for (int s = 0; s < 128; s++)
        rv = fminf(rv, rowpart[(size_t)s * CNT + i]);
    #pragma unroll 8
    for (int s = 0; s < 128; s++)
        cv = fminf(cv, colpart[(size_t)s * CNT + i]);
    float t   = fminf(rv, cv);
    float neg = sqrtf(fmaxf(t, 0.f));
    float pos = sqrtf(fmaxf(post[i], 0.f));
    float local = fmaxf(1.0f - neg + pos, 0.0f);
    #pragma unroll
    for (int m = 1; m < 64; m <<= 1) local += __shfl_xor(local, m, 64);
    __shared__ float wsum[4];
    if ((threadIdx.x & 63) == 0) wsum[threadIdx.x >> 6] = local;
    __syncthreads();
    if (threadIdx.x == 0)
        psum[blockIdx.x] = wsum[0] + wsum[1] + wsum[2] + wsum[3];
}

__global__ __launch_bounds__(64) void finalize2_kernel(
    const float* __restrict__ psum, float* __restrict__ out)
{
    float local = (threadIdx.x < 32) ? psum[threadIdx.x] : 0.f;
    #pragma unroll
    for (int m = 1; m < 64; m <<= 1) local += __shfl_xor(local, m, 64);
    if (threadIdx.x == 0) out[0] = local * (1.0f / (float)CNT);
}

// ---------------- fallback path (round-1, known passing; 96 KB ws) ----------------

#define BM 128
#define BN 128
#define BK 64
#define KST (BK + 8)

typedef __bf16 bf16x8 __attribute__((ext_vector_type(8)));

__global__ __launch_bounds__(256) void init_min_kernel(unsigned* buf, int n) {
    int i = blockIdx.x * 256 + threadIdx.x;
    if (i < n) buf[i] = 0x7F7FFFFFu;
}

__global__ __launch_bounds__(256) void dist_tile_kernel(
    const float* __restrict__ A, const float* __restrict__ P,
    unsigned* __restrict__ g_rowmin, unsigned* __restrict__ g_colmin,
    float* __restrict__ g_pos)
{
    __shared__ unsigned short As[BM * KST];
    __shared__ unsigned short Bs[BN * KST];
    __shared__ unsigned redrow[BM];
    __shared__ unsigned redcol[BN];

    const int tid  = threadIdx.x;
    const int bm   = blockIdx.y;
    const int bn   = blockIdx.x;
    const int wave = tid >> 6;
    const int lane = tid & 63;
    const int quad = lane >> 4;
    const int l15  = lane & 15;
    const int m_off = (wave >> 1) * 64;
    const int n_off = (wave & 1) * 64;

    if (tid < BM) redrow[tid] = 0x7F7FFFFFu;
    if (tid < BN) redcol[tid] = 0x7F7FFFFFu;

    f32x4 acc[4][4];
    #pragma unroll
    for (int i = 0; i < 4; i++)
        #pragma unroll
        for (int j = 0; j < 4; j++)
            acc[i][j] = (f32x4){0.f, 0.f, 0.f, 0.f};

    const int srow = tid >> 4;
    const int scol = tid & 15;

    for (int kc = 0; kc < KDIM / BK; kc++) {
        #pragma unroll
        for (int i = 0; i < 8; i++) {
            int r = srow + i * 16;
            float4 va = *(const float4*)(A + (size_t)(bm * BM + r) * KDIM + kc * BK + scol * 4);
            float4 vb = *(const float4*)(P + (size_t)(bn * BN + r) * KDIM + kc * BK + scol * 4);
            ushort4 wa, wb;
            wa.x = f2bf(va.x); wa.y = f2bf(va.y); wa.z = f2bf(va.z); wa.w = f2bf(va.w);
            wb.x = f2bf(vb.x); wb.y = f2bf(vb.y); wb.z = f2bf(vb.z); wb.w = f2bf(vb.w);
            *(ushort4*)(&As[r * KST + scol * 4]) = wa;
            *(ushort4*)(&Bs[r * KST + scol * 4]) = wb;
        }
        __syncthreads();
        #pragma unroll
        for (int ks = 0; ks < BK / 32; ks++) {
            bf16x8 af[4], bfr[4];
            #pragma unroll
            for (int mi = 0; mi < 4; mi++)
                af[mi] = *(const bf16x8*)(&As[(m_off + mi * 16 + l15) * KST + ks * 32 + quad * 8]);
            #pragma unroll
            for (int ni = 0; ni < 4; ni++)
                bfr[ni] = *(const bf16x8*)(&Bs[(n_off + ni * 16 + l15) * KST + ks * 32 + quad * 8]);
            #pragma unroll
            for (int mi = 0; mi < 4; mi++)
                #pragma unroll
                for (int ni = 0; ni < 4; ni++)
                    acc[mi][ni] = __builtin_amdgcn_mfma_f32_16x16x32_bf16(
                        af[mi], bfr[ni], acc[mi][ni], 0, 0, 0);
        }
        __syncthreads();
    }

    float rmin[4][4], cmin[4];
    #pragma unroll
    for (int mi = 0; mi < 4; mi++)
        #pragma unroll
        for (int r = 0; r < 4; r++) rmin[mi][r] = BIGF;
    #pragma unroll
    for (int ni = 0; ni < 4; ni++) cmin[ni] = BIGF;

    const int grow0 = bm * BM + m_off + quad * 4;
    const int gcol0 = bn * BN + n_off + l15;

    #pragma unroll
    for (int mi = 0; mi < 4; mi++)
        #pragma unroll
        for (int ni = 0; ni < 4; ni++) {
            int gcol = gcol0 + ni * 16;
            #pragma unroll
            for (int r = 0; r < 4; r++) {
                int grow = grow0 + mi * 16 + r;
                float s = acc[mi][ni][r];
                float d = sqrtf((1.0f - s + 1e-6f) * 2.0f);
                float dm = d;
                if (grow == gcol) { g_pos[grow] = d; dm = BIGF; }
                rmin[mi][r] = fminf(rmin[mi][r], dm);
                cmin[ni]    = fminf(cmin[ni], dm);
            }
        }

    #pragma unroll
    for (int mi = 0; mi < 4; mi++)
        #pragma unroll
        for (int r = 0; r < 4; r++) {
            float v = rmin[mi][r];
            v = fminf(v, __shfl_xor(v, 1, 64));
            v = fminf(v, __shfl_xor(v, 2, 64));
            v = fminf(v, __shfl_xor(v, 4, 64));
            v = fminf(v, __shfl_xor(v, 8, 64));
            rmin[mi][r] = v;
        }
    #pragma unroll
    for (int ni = 0; ni < 4; ni++) {
        float v = cmin[ni];
        v = fminf(v, __shfl_xor(v, 16, 64));
        v = fminf(v, __shfl_xor(v, 32, 64));
        cmin[ni] = v;
    }

    if (l15 == 0) {
        #pragma unroll
        for (int mi = 0; mi < 4; mi++)
            #pragma unroll
            for (int r = 0; r < 4; r++)
                atomicMin(&redrow[m_off + mi * 16 + quad * 4 + r],
                          __float_as_uint(rmin[mi][r]));
    }
    if (quad == 0) {
        #pragma unroll
        for (int ni = 0; ni < 4; ni++)
            atomicMin(&redcol[n_off + ni * 16 + l15], __float_as_uint(cmin[ni]));
    }
    __syncthreads();

    if (tid < 128) atomicMin(&g_rowmin[bm * BM + tid], redrow[tid]);
    else           atomicMin(&g_colmin[bn * BN + (tid - 128)], redcol[tid - 128]);
}

__global__ __launch_bounds__(1024) void finalize_kernel(
    const unsigned* __restrict__ g_rowmin, const unsigned* __restrict__ g_colmin,
    const float* __restrict__ g_pos, float* __restrict__ out)
{
    float local = 0.f;
    for (int i = threadIdx.x; i < CNT; i += 1024) {
        float neg = fminf(__uint_as_float(g_rowmin[i]), __uint_as_float(g_colmin[i]));
        float v = 1.0f - neg + g_pos[i];
        local += fmaxf(v, 0.0f);
    }
    #pragma unroll
    for (int m = 1; m < 64; m <<= 1) local += __shfl_xor(local, m, 64);
    __shared__ float wsum[16];
    if ((threadIdx.x & 63) == 0) wsum[threadIdx.x >> 6] = local;
    __syncthreads();
    if (threadIdx.x == 0) {
        float s = 0.f;
        #pragma unroll
        for (int w = 0; w < 16; w++) s += wsum[w];
        out[0] = s * (1.0f / (float)CNT);
    }
}

// ---------------- host ----------------

extern "C" void kernel_launch(void* const* d_in, const int* in_sizes, int n_in,
                              void* d_out, int out_size, void* d_ws, size_t ws_size,
                              hipStream_t stream) {
    const float* x = (const float*)d_in[0];
    float* out = (float*)d_out;

    const size_t fp8_bytes = (size_t)2 * CNT * KDIM;        // 4,194,304
    const size_t part_f    = (size_t)(128 + 128) * CNT;     // rowpart+colpart
    const size_t need = fp8_bytes + part_f * 4 + (size_t)CNT * 4 + 32 * 4;

    if (ws_size >= need) {
        unsigned char* xb      = (unsigned char*)d_ws;
        float*         rowpart = (float*)((char*)d_ws + fp8_bytes);
        float*         colpart = rowpart + (size_t)128 * CNT;
        float*         pos     = colpart + (size_t)128 * CNT;
        float*         psum    = pos + CNT;
        convert_mx_kernel<<<dim3(1024), dim3(256), 0, stream>>>(x, xb);
        dist16_kernel<<<dim3(4096), dim3(256), 0, stream>>>(
            xb, xb + (size_t)CNT * KDIM, rowpart, colpart, pos);
        finalize1_kernel<<<dim3(32), dim3(256), 0, stream>>>(
            rowpart, colpart, pos, psum);
        finalize2_kernel<<<dim3(1), dim3(64), 0, stream>>>(psum, out);
    } else {
        unsigned* rowmin = (unsigned*)d_ws;
        unsigned* colmin = rowmin + CNT;
        float*    pos    = (float*)(colmin + CNT);
        init_min_kernel<<<dim3(2 * CNT / 256), dim3(256), 0, stream>>>(rowmin, 2 * CNT);
        dist_tile_kernel<<<dim3(CNT / BN, CNT / BM), dim3(256), 0, stream>>>(
            x, x + (size_t)CNT * KDIM, rowmin, colmin, pos);
        finalize_kernel<<<dim3(1), dim3(1024), 0, stream>>>(rowmin, colmin, pos, out);
    }
}

// Round 7
// 132.231 us; speedup vs baseline: 1.4719x; 1.4719x over previous
//
#include <hip/hip_runtime.h>
#include <hip/hip_fp8.h>

// HardNetLoss: a = x[:8192], p = x[8192:], d_ij = sqrt((1 - a_i·p_j + 1e-6)*2)
// pos_i = d_ii ; neg_i = min(min_{j!=i} d_ji, min_{j!=i} d_ij)
// out = mean(relu(1 - neg + pos))
//
// R17: R16's counters showed WRITE_SIZE 158MB -- the single-lane (l31==0)
// scattered row-partial stores caused ~64B/4B write amplification; the
// occupancy lever itself WORKED (Occ 17.7->37%, VALU 13->22%). Fix: keep
// R16's 128x128 / 32KB-LDS / 4-blocks-per-CU structure, but route both
// reductions through a 2KB LDS scratch (aliased on dead P buffer after a
// barrier) and emit coalesced 512B stores from 256 threads; min-combine
// wave halves in LDS so slabs halve (64 row + 64 col, 4MB total).
// Per-block global writes ~1.2KB, all full-cacheline.
// 32x32 C/D layout: col = lane&31, row = (reg&3)+8*(reg>>2)+4*(lane>>5).

#define CNT    8192
#define KDIM   256
#define BIGF   3.0e38f
#define SCALE1 0x7F7F7F7F            // 4x e8m0 bytes, each = 2^0

typedef float f32x4  __attribute__((ext_vector_type(4)));
typedef float f32x16 __attribute__((ext_vector_type(16)));
typedef int   v8i    __attribute__((ext_vector_type(8)));

union frag8 { uint4 q[2]; v8i v; };

__device__ __forceinline__ unsigned short f2bf(float f) {
    unsigned u = __float_as_uint(f);
    u += 0x7FFFu + ((u >> 16) & 1u);          // round-to-nearest-even
    return (unsigned short)(u >> 16);
}

__device__ __forceinline__ unsigned cvt4_fp8(float a, float b, float c, float d) {
#if __has_builtin(__builtin_amdgcn_cvt_pk_fp8_f32)
    unsigned v = __builtin_amdgcn_cvt_pk_fp8_f32(a, b, 0, false);
    v = __builtin_amdgcn_cvt_pk_fp8_f32(c, d, v, true);
    return v;
#else
    return (unsigned)__hip_fp8_e4m3(a).__x |
           ((unsigned)__hip_fp8_e4m3(b).__x << 8) |
           ((unsigned)__hip_fp8_e4m3(c).__x << 16) |
           ((unsigned)__hip_fp8_e4m3(d).__x << 24);
#endif
}

// ---------------- fast path ----------------

// x fp32 [16384][256] -> xb fp8, MX-fragment-packed. Chunk (rg32, kc64) is
// 2KB: half h holds j 0..15 (h=0) / 16..31 (h=1) of each lane's 32-k block;
// lane = (row%32) + 32*((col%64)/32). Thread T writes 16B at xb + T*16.
__global__ __launch_bounds__(256) void convert_mx_kernel(
    const float* __restrict__ x, unsigned char* __restrict__ xb)
{
    int T    = blockIdx.x * 256 + threadIdx.x;   // 262144 threads
    int lane = T & 63;
    int h    = (T >> 6) & 1;
    int c    = T >> 7;                           // chunk 0..2047
    int kc64 = c & 3;
    int rg   = c >> 2;                           // 32-row group
    int row  = rg * 32 + (lane & 31);
    int col0 = kc64 * 64 + (lane >> 5) * 32 + h * 16;
    const float* src = x + (size_t)row * KDIM + col0;
    float4 u0 = *(const float4*)(src);
    float4 u1 = *(const float4*)(src + 4);
    float4 u2 = *(const float4*)(src + 8);
    float4 u3 = *(const float4*)(src + 12);
    uint4 w;
    w.x = cvt4_fp8(u0.x, u0.y, u0.z, u0.w);
    w.y = cvt4_fp8(u1.x, u1.y, u1.z, u1.w);
    w.z = cvt4_fp8(u2.x, u2.y, u2.z, u2.w);
    w.w = cvt4_fp8(u3.x, u3.y, u3.z, u3.w);
    *(uint4*)(xb + (size_t)T * 16) = w;
}

// block tile 128(m) x 128(n); 4 waves 2x2; wave tile 64x64 of 32x32x64 MFMA.
__global__ __launch_bounds__(256, 4) void dist17_kernel(
    const unsigned char* __restrict__ Ab_, const unsigned char* __restrict__ Pb_,
    float* __restrict__ rowpart, float* __restrict__ colpart,
    float* __restrict__ g_pos)
{
    __shared__ char smem[32768];                 // P slice; epilogue scratch aliases

    const char* Ab = (const char*)Ab_;
    const char* Pb = (const char*)Pb_;

    const int tid  = threadIdx.x;
    // bijective XCD swizzle: 4096 = 8 xcds x 512; each XCD owns 8 bm2 x all bn2
    const int l    = blockIdx.x;
    const int xcd  = l & 7;
    const int i    = l >> 3;                     // 0..511
    const int bm2  = xcd * 8 + (i & 7);          // 0..63
    const int bn2  = i >> 3;                     // 0..63

    const int wave = tid >> 6;
    const int lane = tid & 63;
    const int l31  = lane & 31;
    const int kh   = lane >> 5;                  // k-half / C-row-half selector
    const int wm   = wave >> 1;                  // 0..1 : m half (64 rows)
    const int wn   = wave & 1;                   // 0..1 : n half (64 cols)

    // stage P slice: rg bn2*4+{0..3} x 4 kc = 16 chunks x 2KB = 32KB.
    // LDS chunk cc = kc*4 + rgl. global_load_lds: dest wave-uniform base,
    // HW adds lane*16 (matches packed layout).
    #pragma unroll
    for (int t = 0; t < 8; t++) {
        const int o   = wave * 8 + t;            // 0..31
        const int cc  = o >> 1;                  // 0..15 : kcs*4 + rgl
        const int h   = o & 1;
        const int rgl = cc & 3;
        const int kcs = cc >> 2;
        const char* src = Pb + (((size_t)(bn2 * 4 + rgl)) << 13)
                             + kcs * 2048 + h * 1024 + lane * 16;
        __builtin_amdgcn_global_load_lds(
            (const __attribute__((address_space(1))) void*)src,
            (__attribute__((address_space(3))) void*)(smem + cc * 2048 + h * 1024),
            16, 0, 0);
    }
    __syncthreads();                             // DMA drain

    f32x16 acc[2][2];
    #pragma unroll
    for (int a = 0; a < 2; a++)
        #pragma unroll
        for (int b = 0; b < 2; b++)
            #pragma unroll
            for (int r = 0; r < 16; r++)
                acc[a][b][r] = 0.f;

    const char* Abase = Ab + lane * 16;
    size_t a_off[2];
    #pragma unroll
    for (int mi = 0; mi < 2; mi++)
        a_off[mi] = (size_t)(bm2 * 4 + wm * 2 + mi) << 13;   // rg32 * 8192

    // K-loop: 4 steps of K=64, no barriers. A from global, B from LDS.
    #pragma unroll
    for (int kc = 0; kc < 4; kc++) {
        frag8 fa[2], fb[2];
        #pragma unroll
        for (int mi = 0; mi < 2; mi++) {
            fa[mi].q[0] = *(const uint4*)(Abase + a_off[mi] + kc * 2048);
            fa[mi].q[1] = *(const uint4*)(Abase + a_off[mi] + kc * 2048 + 1024);
        }
        #pragma unroll
        for (int ni = 0; ni < 2; ni++) {
            const char* p = smem + (kc * 4 + wn * 2 + ni) * 2048 + lane * 16;
            fb[ni].q[0] = *(const uint4*)(p);
            fb[ni].q[1] = *(const uint4*)(p + 1024);
        }
        #pragma unroll
        for (int mi = 0; mi < 2; mi++)
            #pragma unroll
            for (int ni = 0; ni < 2; ni++)
                acc[mi][ni] = __builtin_amdgcn_mfma_scale_f32_32x32x64_f8f6f4(
                    fa[mi].v, fb[ni].v, acc[mi][ni],
                    0, 0,                 // cbsz = fp8 e4m3, blgp = fp8 e4m3
                    0, SCALE1,            // scale_a opsel, scale_a
                    0, SCALE1);           // scale_b opsel, scale_b
    }

    // ---- epilogue. C/D: col = l31, row = (reg&3) + 8*(reg>>2) + 4*kh.
    // local row rl = wm*64 + mi*32 + rowf(reg)   (0..127)
    // local col cl = wn*64 + ni*32 + l31         (0..127)

    if (bm2 == bn2) {                            // diagonal block
        #pragma unroll
        for (int mi = 0; mi < 2; mi++)
            #pragma unroll
            for (int ni = 0; ni < 2; ni++)
                #pragma unroll
                for (int reg = 0; reg < 16; reg++) {
                    int rl = wm * 64 + mi * 32 + (reg & 3) + 8 * (reg >> 2) + 4 * kh;
                    int cl = wn * 64 + ni * 32 + l31;
                    if (cl == rl) {
                        g_pos[bm2 * 128 + rl] = (1.0f - acc[mi][ni][reg] + 1e-6f) * 2.0f;
                        acc[mi][ni][reg] = -BIGF;
                    }
                }
    }

    // LDS scratch (aliases dead P buffer): colred[2][128], rowred[2][128].
    __syncthreads();                             // all P reads complete
    float* colred = (float*)smem;                // [wm][128]
    float* rowred = (float*)smem + 256;          // [wn][128]

    // col-direction (min over this wave's 64 rows => max s): in-lane fold
    // + 1 kh-shuffle; kh==0 lanes write LDS (distinct addrs, no conflict).
    #pragma unroll
    for (int ni = 0; ni < 2; ni++) {
        float v = -BIGF;
        #pragma unroll
        for (int mi = 0; mi < 2; mi++)
            #pragma unroll
            for (int reg = 0; reg < 16; reg++)
                v = fmaxf(v, acc[mi][ni][reg]);
        v = fmaxf(v, __shfl_xor(v, 32, 64));
        if (kh == 0)
            colred[wm * 128 + wn * 64 + ni * 32 + l31] = v;
    }

    // row-direction (min over this wave's 64 cols): in-lane ni-fold, then
    // 5-step shfl_xor butterfly within the 32-lane kh-group; l31==0 writes LDS.
    #pragma unroll
    for (int mi = 0; mi < 2; mi++)
        #pragma unroll
        for (int reg = 0; reg < 16; reg++) {
            float v = fmaxf(acc[mi][0][reg], acc[mi][1][reg]);
            v = fmaxf(v, __shfl_xor(v, 1, 64));
            v = fmaxf(v, __shfl_xor(v, 2, 64));
            v = fmaxf(v, __shfl_xor(v, 4, 64));
            v = fmaxf(v, __shfl_xor(v, 8, 64));
            v = fmaxf(v, __shfl_xor(v, 16, 64));
            if (l31 == 0) {
                int rl = wm * 64 + mi * 32 + (reg & 3) + 8 * (reg >> 2) + 4 * kh;
                rowred[wn * 128 + rl] = v;
            }
        }
    __syncthreads();

    // coalesced 512B stores: combine the two wave-halves, apply transform.
    if (tid < 128) {
        float v = fmaxf(rowred[tid], rowred[128 + tid]);     // min-d = max-s
        float tt = fmaxf((1.0f - v + 1e-6f) * 2.0f, 0.0f);
        rowpart[(size_t)bn2 * CNT + bm2 * 128 + tid] = tt;
    } else {
        int c = tid - 128;
        float v = fmaxf(colred[c], colred[128 + c]);
        float tt = fmaxf((1.0f - v + 1e-6f) * 2.0f, 0.0f);
        colpart[(size_t)bm2 * CNT + bn2 * 128 + c] = tt;
    }
}

// finalize1: 32 blocks x 256 = 8192 threads, one per element. Reduces 64
// rowpart + 64 colpart slabs (coalesced), computes the loss term, stores
// one partial sum per block.
__global__ __launch_bounds__(256) void finalize1_kernel(
    const float* __restrict__ rowpart, const float* __restrict__ colpart,
    const float* __restrict__ post, float* __restrict__ psum)
{
    const int i = blockIdx.x * 256 + threadIdx.x;
    float rv = BIGF, cv = BIGF;
    #pragma unroll 8
    for (int s = 0; s < 64; s++)
        rv = fminf(rv, rowpart[(size_t)s * CNT + i]);
    #pragma unroll 8
    for (int s = 0; s < 64; s++)
        cv = fminf(cv, colpart[(size_t)s * CNT + i]);
    float t   = fminf(rv, cv);
    float neg = sqrtf(fmaxf(t, 0.f));
    float pos = sqrtf(fmaxf(post[i], 0.f));
    float local = fmaxf(1.0f - neg + pos, 0.0f);
    #pragma unroll
    for (int m = 1; m < 64; m <<= 1) local += __shfl_xor(local, m, 64);
    __shared__ float wsum[4];
    if ((threadIdx.x & 63) == 0) wsum[threadIdx.x >> 6] = local;
    __syncthreads();
    if (threadIdx.x == 0)
        psum[blockIdx.x] = wsum[0] + wsum[1] + wsum[2] + wsum[3];
}

__global__ __launch_bounds__(64) void finalize2_kernel(
    const float* __restrict__ psum, float* __restrict__ out)
{
    float local = (threadIdx.x < 32) ? psum[threadIdx.x] : 0.f;
    #pragma unroll
    for (int m = 1; m < 64; m <<= 1) local += __shfl_xor(local, m, 64);
    if (threadIdx.x == 0) out[0] = local * (1.0f / (float)CNT);
}

// ---------------- fallback path (round-1, known passing; 96 KB ws) ----------------

#define BM 128
#define BN 128
#define BK 64
#define KST (BK + 8)

typedef __bf16 bf16x8 __attribute__((ext_vector_type(8)));

__global__ __launch_bounds__(256) void init_min_kernel(unsigned* buf, int n) {
    int i = blockIdx.x * 256 + threadIdx.x;
    if (i < n) buf[i] = 0x7F7FFFFFu;
}

__global__ __launch_bounds__(256) void dist_tile_kernel(
    const float* __restrict__ A, const float* __restrict__ P,
    unsigned* __restrict__ g_rowmin, unsigned* __restrict__ g_colmin,
    float* __restrict__ g_pos)
{
    __shared__ unsigned short As[BM * KST];
    __shared__ unsigned short Bs[BN * KST];
    __shared__ unsigned redrow[BM];
    __shared__ unsigned redcol[BN];

    const int tid  = threadIdx.x;
    const int bm   = blockIdx.y;
    const int bn   = blockIdx.x;
    const int wave = tid >> 6;
    const int lane = tid & 63;
    const int quad = lane >> 4;
    const int l15  = lane & 15;
    const int m_off = (wave >> 1) * 64;
    const int n_off = (wave & 1) * 64;

    if (tid < BM) redrow[tid] = 0x7F7FFFFFu;
    if (tid < BN) redcol[tid] = 0x7F7FFFFFu;

    f32x4 acc[4][4];
    #pragma unroll
    for (int i = 0; i < 4; i++)
        #pragma unroll
        for (int j = 0; j < 4; j++)
            acc[i][j] = (f32x4){0.f, 0.f, 0.f, 0.f};

    const int srow = tid >> 4;
    const int scol = tid & 15;

    for (int kc = 0; kc < KDIM / BK; kc++) {
        #pragma unroll
        for (int i = 0; i < 8; i++) {
            int r = srow + i * 16;
            float4 va = *(const float4*)(A + (size_t)(bm * BM + r) * KDIM + kc * BK + scol * 4);
            float4 vb = *(const float4*)(P + (size_t)(bn * BN + r) * KDIM + kc * BK + scol * 4);
            ushort4 wa, wb;
            wa.x = f2bf(va.x); wa.y = f2bf(va.y); wa.z = f2bf(va.z); wa.w = f2bf(va.w);
            wb.x = f2bf(vb.x); wb.y = f2bf(vb.y); wb.z = f2bf(vb.z); wb.w = f2bf(vb.w);
            *(ushort4*)(&As[r * KST + scol * 4]) = wa;
            *(ushort4*)(&Bs[r * KST + scol * 4]) = wb;
        }
        __syncthreads();
        #pragma unroll
        for (int ks = 0; ks < BK / 32; ks++) {
            bf16x8 af[4], bfr[4];
            #pragma unroll
            for (int mi = 0; mi < 4; mi++)
                af[mi] = *(const bf16x8*)(&As[(m_off + mi * 16 + l15) * KST + ks * 32 + quad * 8]);
            #pragma unroll
            for (int ni = 0; ni < 4; ni++)
                bfr[ni] = *(const bf16x8*)(&Bs[(n_off + ni * 16 + l15) * KST + ks * 32 + quad * 8]);
            #pragma unroll
            for (int mi = 0; mi < 4; mi++)
                #pragma unroll
                for (int ni = 0; ni < 4; ni++)
                    acc[mi][ni] = __builtin_amdgcn_mfma_f32_16x16x32_bf16(
                        af[mi], bfr[ni], acc[mi][ni], 0, 0, 0);
        }
        __syncthreads();
    }

    float rmin[4][4], cmin[4];
    #pragma unroll
    for (int mi = 0; mi < 4; mi++)
        #pragma unroll
        for (int r = 0; r < 4; r++) rmin[mi][r] = BIGF;
    #pragma unroll
    for (int ni = 0; ni < 4; ni++) cmin[ni] = BIGF;

    const int grow0 = bm * BM + m_off + quad * 4;
    const int gcol0 = bn * BN + n_off + l15;

    #pragma unroll
    for (int mi = 0; mi < 4; mi++)
        #pragma unroll
        for (int ni = 0; ni < 4; ni++) {
            int gcol = gcol0 + ni * 16;
            #pragma unroll
            for (int r = 0; r < 4; r++) {
                int grow = grow0 + mi * 16 + r;
                float s = acc[mi][ni][r];
                float d = sqrtf((1.0f - s + 1e-6f) * 2.0f);
                float dm = d;
                if (grow == gcol) { g_pos[grow] = d; dm = BIGF; }
                rmin[mi][r] = fminf(rmin[mi][r], dm);
                cmin[ni]    = fminf(cmin[ni], dm);
            }
        }

    #pragma unroll
    for (int mi = 0; mi < 4; mi++)
        #pragma unroll
        for (int r = 0; r < 4; r++) {
            float v = rmin[mi][r];
            v = fminf(v, __shfl_xor(v, 1, 64));
            v = fminf(v, __shfl_xor(v, 2, 64));
            v = fminf(v, __shfl_xor(v, 4, 64));
            v = fminf(v, __shfl_xor(v, 8, 64));
            rmin[mi][r] = v;
        }
    #pragma unroll
    for (int ni = 0; ni < 4; ni++) {
        float v = cmin[ni];
        v = fminf(v, __shfl_xor(v, 16, 64));
        v = fminf(v, __shfl_xor(v, 32, 64));
        cmin[ni] = v;
    }

    if (l15 == 0) {
        #pragma unroll
        for (int mi = 0; mi < 4; mi++)
            #pragma unroll
            for (int r = 0; r < 4; r++)
                atomicMin(&redrow[m_off + mi * 16 + quad * 4 + r],
                          __float_as_uint(rmin[mi][r]));
    }
    if (quad == 0) {
        #pragma unroll
        for (int ni = 0; ni < 4; ni++)
            atomicMin(&redcol[n_off + ni * 16 + l15], __float_as_uint(cmin[ni]));
    }
    __syncthreads();

    if (tid < 128) atomicMin(&g_rowmin[bm * BM + tid], redrow[tid]);
    else           atomicMin(&g_colmin[bn * BN + (tid - 128)], redcol[tid - 128]);
}

__global__ __launch_bounds__(1024) void finalize_kernel(
    const unsigned* __restrict__ g_rowmin, const unsigned* __restrict__ g_colmin,
    const float* __restrict__ g_pos, float* __restrict__ out)
{
    float local = 0.f;
    for (int i = threadIdx.x; i < CNT; i += 1024) {
        float neg = fminf(__uint_as_float(g_rowmin[i]), __uint_as_float(g_colmin[i]));
        float v = 1.0f - neg + g_pos[i];
        local += fmaxf(v, 0.0f);
    }
    #pragma unroll
    for (int m = 1; m < 64; m <<= 1) local += __shfl_xor(local, m, 64);
    __shared__ float wsum[16];
    if ((threadIdx.x & 63) == 0) wsum[threadIdx.x >> 6] = local;
    __syncthreads();
    if (threadIdx.x == 0) {
        float s = 0.f;
        #pragma unroll
        for (int w = 0; w < 16; w++) s += wsum[w];
        out[0] = s * (1.0f / (float)CNT);
    }
}

// ---------------- host ----------------

extern "C" void kernel_launch(void* const* d_in, const int* in_sizes, int n_in,
                              void* d_out, int out_size, void* d_ws, size_t ws_size,
                              hipStream_t stream) {
    const float* x = (const float*)d_in[0];
    float* out = (float*)d_out;

    const size_t fp8_bytes = (size_t)2 * CNT * KDIM;        // 4,194,304
    const size_t part_f    = (size_t)(64 + 64) * CNT;       // rowpart+colpart
    const size_t need = fp8_bytes + part_f * 4 + (size_t)CNT * 4 + 32 * 4;

    if (ws_size >= need) {
        unsigned char* xb      = (unsigned char*)d_ws;
        float*         rowpart = (float*)((char*)d_ws + fp8_bytes);
        float*         colpart = rowpart + (size_t)64 * CNT;
        float*         pos     = colpart + (size_t)64 * CNT;
        float*         psum    = pos + CNT;
        convert_mx_kernel<<<dim3(1024), dim3(256), 0, stream>>>(x, xb);
        dist17_kernel<<<dim3(4096), dim3(256), 0, stream>>>(
            xb, xb + (size_t)CNT * KDIM, rowpart, colpart, pos);
        finalize1_kernel<<<dim3(32), dim3(256), 0, stream>>>(
            rowpart, colpart, pos, psum);
        finalize2_kernel<<<dim3(1), dim3(64), 0, stream>>>(psum, out);
    } else {
        unsigned* rowmin = (unsigned*)d_ws;
        unsigned* colmin = rowmin + CNT;
        float*    pos    = (float*)(colmin + CNT);
        init_min_kernel<<<dim3(2 * CNT / 256), dim3(256), 0, stream>>>(rowmin, 2 * CNT);
        dist_tile_kernel<<<dim3(CNT / BN, CNT / BM), dim3(256), 0, stream>>>(
            x, x + (size_t)CNT * KDIM, rowmin, colmin, pos);
        finalize_kernel<<<dim3(1), dim3(1024), 0, stream>>>(rowmin, colmin, pos, out);
    }
}

// Round 8
// 128.839 us; speedup vs baseline: 1.5107x; 1.0263x over previous
//
#include <hip/hip_runtime.h>
#include <hip/hip_fp8.h>

// HardNetLoss: a = x[:8192], p = x[8192:], d_ij = sqrt((1 - a_i·p_j + 1e-6)*2)
// pos_i = d_ii ; neg_i = min(min_{j!=i} d_ji, min_{j!=i} d_ij)
// out = mean(relu(1 - neg + pos))
//
// R18: R17 fixed WRITE_SIZE (158->4MB) but dist regressed 31->51us: the
// 128x128 tile raised L2 feed to 393MB (A dup x2, 6B/elem) while halving
// MFMA density. Across R10-R17: feed-down alone null, atomics-down alone
// null, occupancy-up with feed-up regressed. R18 hits the untried corner,
// feed-down AND occupancy-up: 256x256 tile, 1024 threads (16 waves 4x4),
// BOTH operands staged in LDS (128KB, m201 precedent) -> zero wave dup,
// total L2 feed 131MB (half of R15); wave tile 64x64 (acc 64 VGPR),
// launch_bounds(1024,4) caps VGPR<=128 -> 16 waves/CU = 4/SIMD (2x R15).
// Grid 1024 = 4 sequential blocks/CU; 16-wave TLP replaces cross-block
// overlap. Epilogue: butterfly row-reduce + 8KB scratch aliased on dead
// staging LDS, coalesced 2KB/block stores (R17's clean write path).
// 32x32 C/D layout: col = lane&31, row = (reg&3)+8*(reg>>2)+4*(lane>>5).

#define CNT    8192
#define KDIM   256
#define BIGF   3.0e38f
#define SCALE1 0x7F7F7F7F            // 4x e8m0 bytes, each = 2^0

typedef float f32x4  __attribute__((ext_vector_type(4)));
typedef float f32x16 __attribute__((ext_vector_type(16)));
typedef int   v8i    __attribute__((ext_vector_type(8)));

union frag8 { uint4 q[2]; v8i v; };

__device__ __forceinline__ unsigned short f2bf(float f) {
    unsigned u = __float_as_uint(f);
    u += 0x7FFFu + ((u >> 16) & 1u);          // round-to-nearest-even
    return (unsigned short)(u >> 16);
}

__device__ __forceinline__ unsigned cvt4_fp8(float a, float b, float c, float d) {
#if __has_builtin(__builtin_amdgcn_cvt_pk_fp8_f32)
    unsigned v = __builtin_amdgcn_cvt_pk_fp8_f32(a, b, 0, false);
    v = __builtin_amdgcn_cvt_pk_fp8_f32(c, d, v, true);
    return v;
#else
    return (unsigned)__hip_fp8_e4m3(a).__x |
           ((unsigned)__hip_fp8_e4m3(b).__x << 8) |
           ((unsigned)__hip_fp8_e4m3(c).__x << 16) |
           ((unsigned)__hip_fp8_e4m3(d).__x << 24);
#endif
}

// ---------------- fast path ----------------

// x fp32 [16384][256] -> xb fp8, MX-fragment-packed. Chunk (rg32, kc64) is
// 2KB: half h holds j 0..15 (h=0) / 16..31 (h=1) of each lane's 32-k block;
// lane = (row%32) + 32*((col%64)/32). Thread T writes 16B at xb + T*16.
__global__ __launch_bounds__(256) void convert_mx_kernel(
    const float* __restrict__ x, unsigned char* __restrict__ xb)
{
    int T    = blockIdx.x * 256 + threadIdx.x;   // 262144 threads
    int lane = T & 63;
    int h    = (T >> 6) & 1;
    int c    = T >> 7;                           // chunk 0..2047
    int kc64 = c & 3;
    int rg   = c >> 2;                           // 32-row group
    int row  = rg * 32 + (lane & 31);
    int col0 = kc64 * 64 + (lane >> 5) * 32 + h * 16;
    const float* src = x + (size_t)row * KDIM + col0;
    float4 u0 = *(const float4*)(src);
    float4 u1 = *(const float4*)(src + 4);
    float4 u2 = *(const float4*)(src + 8);
    float4 u3 = *(const float4*)(src + 12);
    uint4 w;
    w.x = cvt4_fp8(u0.x, u0.y, u0.z, u0.w);
    w.y = cvt4_fp8(u1.x, u1.y, u1.z, u1.w);
    w.z = cvt4_fp8(u2.x, u2.y, u2.z, u2.w);
    w.w = cvt4_fp8(u3.x, u3.y, u3.z, u3.w);
    *(uint4*)(xb + (size_t)T * 16) = w;
}

// block tile 256(m) x 256(n); 16 waves 4x4; wave tile 64x64 of 32x32x64 MFMA.
// A and P each: 8 rg-chunks x 4 kc = 32 chunks x 2KB = 64KB in LDS,
// layout cc = kc*8 + rgl. Zero wave duplication of L2 traffic.
__global__ __launch_bounds__(1024, 4) void dist18_kernel(
    const unsigned char* __restrict__ Ab_, const unsigned char* __restrict__ Pb_,
    float* __restrict__ rowpart, float* __restrict__ colpart,
    float* __restrict__ g_pos)
{
    __shared__ char smem[131072];                // A [0,64K) + P [64K,128K)

    const char* Ab = (const char*)Ab_;
    const char* Pb = (const char*)Pb_;

    const int tid  = threadIdx.x;
    // bijective XCD swizzle: 1024 = 8 xcds x 128; each XCD owns 4 bm3 x all bn3
    const int l    = blockIdx.x;
    const int xcd  = l & 7;
    const int i    = l >> 3;                     // 0..127
    const int bm3  = xcd * 4 + (i & 3);          // 0..31
    const int bn3  = i >> 2;                     // 0..31

    const int wave = tid >> 6;                   // 0..15
    const int lane = tid & 63;
    const int l31  = lane & 31;
    const int kh   = lane >> 5;                  // k-half / C-row-half selector
    const int wm   = wave >> 2;                  // 0..3 : m strip (64 rows)
    const int wn   = wave & 3;                   // 0..3 : n strip (64 cols)

    // stage A+P: 128 half-chunks of 1KB, 8 per wave. global_load_lds dest is
    // wave-uniform base, HW adds lane*16 (matches packed layout).
    #pragma unroll
    for (int t = 0; t < 8; t++) {
        const int o   = wave * 8 + t;            // 0..127
        const int ab  = o >> 6;                  // 0 = A, 1 = P
        const int oo  = o & 63;
        const int cc  = oo >> 1;                 // 0..31 : kcs*8 + rgl
        const int h   = oo & 1;
        const int rgl = cc & 7;
        const int kcs = cc >> 3;
        const char* base = ab ? Pb : Ab;
        const int   bx   = ab ? bn3 : bm3;
        const char* src  = base + (((size_t)(bx * 8 + rgl)) << 13)
                                + kcs * 2048 + h * 1024 + lane * 16;
        __builtin_amdgcn_global_load_lds(
            (const __attribute__((address_space(1))) void*)src,
            (__attribute__((address_space(3))) void*)(smem + ab * 65536
                                                      + cc * 2048 + h * 1024),
            16, 0, 0);
    }
    __syncthreads();                             // DMA drain

    f32x16 acc[2][2];
    #pragma unroll
    for (int a = 0; a < 2; a++)
        #pragma unroll
        for (int b = 0; b < 2; b++)
            #pragma unroll
            for (int r = 0; r < 16; r++)
                acc[a][b][r] = 0.f;

    // K-loop: 4 steps of K=64, no barriers; both operands ds_read_b128
    // (lane-linear, conflict-free; compiler schedules lgkmcnt).
    #pragma unroll
    for (int kc = 0; kc < 4; kc++) {
        frag8 fa[2], fb[2];
        #pragma unroll
        for (int mi = 0; mi < 2; mi++) {
            const char* p = smem + (kc * 8 + wm * 2 + mi) * 2048 + lane * 16;
            fa[mi].q[0] = *(const uint4*)(p);
            fa[mi].q[1] = *(const uint4*)(p + 1024);
        }
        #pragma unroll
        for (int ni = 0; ni < 2; ni++) {
            const char* p = smem + 65536 + (kc * 8 + wn * 2 + ni) * 2048 + lane * 16;
            fb[ni].q[0] = *(const uint4*)(p);
            fb[ni].q[1] = *(const uint4*)(p + 1024);
        }
        #pragma unroll
        for (int mi = 0; mi < 2; mi++)
            #pragma unroll
            for (int ni = 0; ni < 2; ni++)
                acc[mi][ni] = __builtin_amdgcn_mfma_scale_f32_32x32x64_f8f6f4(
                    fa[mi].v, fb[ni].v, acc[mi][ni],
                    0, 0,                 // cbsz = fp8 e4m3, blgp = fp8 e4m3
                    0, SCALE1,            // scale_a opsel, scale_a
                    0, SCALE1);           // scale_b opsel, scale_b
    }

    // ---- epilogue. C/D: col = l31, row = (reg&3) + 8*(reg>>2) + 4*kh.
    // local row rl = wm*64 + mi*32 + rowf(reg)   (0..255)
    // local col cl = wn*64 + ni*32 + l31         (0..255)

    if (bm3 == bn3) {                            // diagonal block
        #pragma unroll
        for (int mi = 0; mi < 2; mi++)
            #pragma unroll
            for (int ni = 0; ni < 2; ni++)
                #pragma unroll
                for (int reg = 0; reg < 16; reg++) {
                    int rl = wm * 64 + mi * 32 + (reg & 3) + 8 * (reg >> 2) + 4 * kh;
                    int cl = wn * 64 + ni * 32 + l31;
                    if (cl == rl) {
                        g_pos[bm3 * 256 + rl] = (1.0f - acc[mi][ni][reg] + 1e-6f) * 2.0f;
                        acc[mi][ni][reg] = -BIGF;
                    }
                }
    }

    // LDS scratch aliases dead staging: colred[4][256], rowred[4][256].
    __syncthreads();                             // all K-loop LDS reads done
    float* colred = (float*)smem;                // [wm][256]
    float* rowred = (float*)smem + 1024;         // [wn][256]

    // col-direction (min over this wave's 64 rows => max s): in-lane fold
    // over mi,reg + 1 kh-shuffle; kh==0 lanes write LDS (disjoint addrs).
    #pragma unroll
    for (int ni = 0; ni < 2; ni++) {
        float v = -BIGF;
        #pragma unroll
        for (int mi = 0; mi < 2; mi++)
            #pragma unroll
            for (int reg = 0; reg < 16; reg++)
                v = fmaxf(v, acc[mi][ni][reg]);
        v = fmaxf(v, __shfl_xor(v, 32, 64));
        if (kh == 0)
            colred[wm * 256 + wn * 64 + ni * 32 + l31] = v;
    }

    // row-direction (min over this wave's 64 cols): in-lane ni-fold, then
    // 5-step shfl_xor butterfly within the 32-lane kh-group; l31==0 writes.
    #pragma unroll
    for (int mi = 0; mi < 2; mi++)
        #pragma unroll
        for (int reg = 0; reg < 16; reg++) {
            float v = fmaxf(acc[mi][0][reg], acc[mi][1][reg]);
            v = fmaxf(v, __shfl_xor(v, 1, 64));
            v = fmaxf(v, __shfl_xor(v, 2, 64));
            v = fmaxf(v, __shfl_xor(v, 4, 64));
            v = fmaxf(v, __shfl_xor(v, 8, 64));
            v = fmaxf(v, __shfl_xor(v, 16, 64));
            if (l31 == 0) {
                int rl = wm * 64 + mi * 32 + (reg & 3) + 8 * (reg >> 2) + 4 * kh;
                rowred[wn * 256 + rl] = v;
            }
        }
    __syncthreads();

    // coalesced 1KB-segment stores: combine the 4 wave-strips, transform.
    if (tid < 256) {
        float v = fmaxf(fmaxf(rowred[tid], rowred[256 + tid]),
                        fmaxf(rowred[512 + tid], rowred[768 + tid]));
        float tt = fmaxf((1.0f - v + 1e-6f) * 2.0f, 0.0f);
        rowpart[(size_t)bn3 * CNT + bm3 * 256 + tid] = tt;
    } else if (tid < 512) {
        int c = tid - 256;
        float v = fmaxf(fmaxf(colred[c], colred[256 + c]),
                        fmaxf(colred[512 + c], colred[768 + c]));
        float tt = fmaxf((1.0f - v + 1e-6f) * 2.0f, 0.0f);
        colpart[(size_t)bm3 * CNT + bn3 * 256 + c] = tt;
    }
}

// finalize1: 32 blocks x 256 = 8192 threads, one per element. Reduces 32
// rowpart + 32 colpart slabs (coalesced), computes the loss term, stores
// one partial sum per block.
__global__ __launch_bounds__(256) void finalize1_kernel(
    const float* __restrict__ rowpart, const float* __restrict__ colpart,
    const float* __restrict__ post, float* __restrict__ psum)
{
    const int i = blockIdx.x * 256 + threadIdx.x;
    float rv = BIGF, cv = BIGF;
    #pragma unroll 8
    for (int s = 0; s < 32; s++)
        rv = fminf(rv, rowpart[(size_t)s * CNT + i]);
    #pragma unroll 8
    for (int s = 0; s < 32; s++)
        cv = fminf(cv, colpart[(size_t)s * CNT + i]);
    float t   = fminf(rv, cv);
    float neg = sqrtf(fmaxf(t, 0.f));
    float pos = sqrtf(fmaxf(post[i], 0.f));
    float local = fmaxf(1.0f - neg + pos, 0.0f);
    #pragma unroll
    for (int m = 1; m < 64; m <<= 1) local += __shfl_xor(local, m, 64);
    __shared__ float wsum[4];
    if ((threadIdx.x & 63) == 0) wsum[threadIdx.x >> 6] = local;
    __syncthreads();
    if (threadIdx.x == 0)
        psum[blockIdx.x] = wsum[0] + wsum[1] + wsum[2] + wsum[3];
}

__global__ __launch_bounds__(64) void finalize2_kernel(
    const float* __restrict__ psum, float* __restrict__ out)
{
    float local = (threadIdx.x < 32) ? psum[threadIdx.x] : 0.f;
    #pragma unroll
    for (int m = 1; m < 64; m <<= 1) local += __shfl_xor(local, m, 64);
    if (threadIdx.x == 0) out[0] = local * (1.0f / (float)CNT);
}

// ---------------- fallback path (round-1, known passing; 96 KB ws) ----------------

#define BM 128
#define BN 128
#define BK 64
#define KST (BK + 8)

typedef __bf16 bf16x8 __attribute__((ext_vector_type(8)));

__global__ __launch_bounds__(256) void init_min_kernel(unsigned* buf, int n) {
    int i = blockIdx.x * 256 + threadIdx.x;
    if (i < n) buf[i] = 0x7F7FFFFFu;
}

__global__ __launch_bounds__(256) void dist_tile_kernel(
    const float* __restrict__ A, const float* __restrict__ P,
    unsigned* __restrict__ g_rowmin, unsigned* __restrict__ g_colmin,
    float* __restrict__ g_pos)
{
    __shared__ unsigned short As[BM * KST];
    __shared__ unsigned short Bs[BN * KST];
    __shared__ unsigned redrow[BM];
    __shared__ unsigned redcol[BN];

    const int tid  = threadIdx.x;
    const int bm   = blockIdx.y;
    const int bn   = blockIdx.x;
    const int wave = tid >> 6;
    const int lane = tid & 63;
    const int quad = lane >> 4;
    const int l15  = lane & 15;
    const int m_off = (wave >> 1) * 64;
    const int n_off = (wave & 1) * 64;

    if (tid < BM) redrow[tid] = 0x7F7FFFFFu;
    if (tid < BN) redcol[tid] = 0x7F7FFFFFu;

    f32x4 acc[4][4];
    #pragma unroll
    for (int i = 0; i < 4; i++)
        #pragma unroll
        for (int j = 0; j < 4; j++)
            acc[i][j] = (f32x4){0.f, 0.f, 0.f, 0.f};

    const int srow = tid >> 4;
    const int scol = tid & 15;

    for (int kc = 0; kc < KDIM / BK; kc++) {
        #pragma unroll
        for (int i = 0; i < 8; i++) {
            int r = srow + i * 16;
            float4 va = *(const float4*)(A + (size_t)(bm * BM + r) * KDIM + kc * BK + scol * 4);
            float4 vb = *(const float4*)(P + (size_t)(bn * BN + r) * KDIM + kc * BK + scol * 4);
            ushort4 wa, wb;
            wa.x = f2bf(va.x); wa.y = f2bf(va.y); wa.z = f2bf(va.z); wa.w = f2bf(va.w);
            wb.x = f2bf(vb.x); wb.y = f2bf(vb.y); wb.z = f2bf(vb.z); wb.w = f2bf(vb.w);
            *(ushort4*)(&As[r * KST + scol * 4]) = wa;
            *(ushort4*)(&Bs[r * KST + scol * 4]) = wb;
        }
        __syncthreads();
        #pragma unroll
        for (int ks = 0; ks < BK / 32; ks++) {
            bf16x8 af[4], bfr[4];
            #pragma unroll
            for (int mi = 0; mi < 4; mi++)
                af[mi] = *(const bf16x8*)(&As[(m_off + mi * 16 + l15) * KST + ks * 32 + quad * 8]);
            #pragma unroll
            for (int ni = 0; ni < 4; ni++)
                bfr[ni] = *(const bf16x8*)(&Bs[(n_off + ni * 16 + l15) * KST + ks * 32 + quad * 8]);
            #pragma unroll
            for (int mi = 0; mi < 4; mi++)
                #pragma unroll
                for (int ni = 0; ni < 4; ni++)
                    acc[mi][ni] = __builtin_amdgcn_mfma_f32_16x16x32_bf16(
                        af[mi], bfr[ni], acc[mi][ni], 0, 0, 0);
        }
        __syncthreads();
    }

    float rmin[4][4], cmin[4];
    #pragma unroll
    for (int mi = 0; mi < 4; mi++)
        #pragma unroll
        for (int r = 0; r < 4; r++) rmin[mi][r] = BIGF;
    #pragma unroll
    for (int ni = 0; ni < 4; ni++) cmin[ni] = BIGF;

    const int grow0 = bm * BM + m_off + quad * 4;
    const int gcol0 = bn * BN + n_off + l15;

    #pragma unroll
    for (int mi = 0; mi < 4; mi++)
        #pragma unroll
        for (int ni = 0; ni < 4; ni++) {
            int gcol = gcol0 + ni * 16;
            #pragma unroll
            for (int r = 0; r < 4; r++) {
                int grow = grow0 + mi * 16 + r;
                float s = acc[mi][ni][r];
                float d = sqrtf((1.0f - s + 1e-6f) * 2.0f);
                float dm = d;
                if (grow == gcol) { g_pos[grow] = d; dm = BIGF; }
                rmin[mi][r] = fminf(rmin[mi][r], dm);
                cmin[ni]    = fminf(cmin[ni], dm);
            }
        }

    #pragma unroll
    for (int mi = 0; mi < 4; mi++)
        #pragma unroll
        for (int r = 0; r < 4; r++) {
            float v = rmin[mi][r];
            v = fminf(v, __shfl_xor(v, 1, 64));
            v = fminf(v, __shfl_xor(v, 2, 64));
            v = fminf(v, __shfl_xor(v, 4, 64));
            v = fminf(v, __shfl_xor(v, 8, 64));
            rmin[mi][r] = v;
        }
    #pragma unroll
    for (int ni = 0; ni < 4; ni++) {
        float v = cmin[ni];
        v = fminf(v, __shfl_xor(v, 16, 64));
        v = fminf(v, __shfl_xor(v, 32, 64));
        cmin[ni] = v;
    }

    if (l15 == 0) {
        #pragma unroll
        for (int mi = 0; mi < 4; mi++)
            #pragma unroll
            for (int r = 0; r < 4; r++)
                atomicMin(&redrow[m_off + mi * 16 + quad * 4 + r],
                          __float_as_uint(rmin[mi][r]));
    }
    if (quad == 0) {
        #pragma unroll
        for (int ni = 0; ni < 4; ni++)
            atomicMin(&redcol[n_off + ni * 16 + l15], __float_as_uint(cmin[ni]));
    }
    __syncthreads();

    if (tid < 128) atomicMin(&g_rowmin[bm * BM + tid], redrow[tid]);
    else           atomicMin(&g_colmin[bn * BN + (tid - 128)], redcol[tid - 128]);
}

__global__ __launch_bounds__(1024) void finalize_kernel(
    const unsigned* __restrict__ g_rowmin, const unsigned* __restrict__ g_colmin,
    const float* __restrict__ g_pos, float* __restrict__ out)
{
    float local = 0.f;
    for (int i = threadIdx.x; i < CNT; i += 1024) {
        float neg = fminf(__uint_as_float(g_rowmin[i]), __uint_as_float(g_colmin[i]));
        float v = 1.0f - neg + g_pos[i];
        local += fmaxf(v, 0.0f);
    }
    #pragma unroll
    for (int m = 1; m < 64; m <<= 1) local += __shfl_xor(local, m, 64);
    __shared__ float wsum[16];
    if ((threadIdx.x & 63) == 0) wsum[threadIdx.x >> 6] = local;
    __syncthreads();
    if (threadIdx.x == 0) {
        float s = 0.f;
        #pragma unroll
        for (int w = 0; w < 16; w++) s += wsum[w];
        out[0] = s * (1.0f / (float)CNT);
    }
}

// ---------------- host ----------------

extern "C" void kernel_launch(void* const* d_in, const int* in_sizes, int n_in,
                              void* d_out, int out_size, void* d_ws, size_t ws_size,
                              hipStream_t stream) {
    const float* x = (const float*)d_in[0];
    float* out = (float*)d_out;

    const size_t fp8_bytes = (size_t)2 * CNT * KDIM;        // 4,194,304
    const size_t part_f    = (size_t)(32 + 32) * CNT;       // rowpart+colpart
    const size_t need = fp8_bytes + part_f * 4 + (size_t)CNT * 4 + 32 * 4;

    if (ws_size >= need) {
        unsigned char* xb      = (unsigned char*)d_ws;
        float*         rowpart = (float*)((char*)d_ws + fp8_bytes);
        float*         colpart = rowpart + (size_t)32 * CNT;
        float*         pos     = colpart + (size_t)32 * CNT;
        float*         psum    = pos + CNT;
        convert_mx_kernel<<<dim3(1024), dim3(256), 0, stream>>>(x, xb);
        dist18_kernel<<<dim3(1024), dim3(1024), 0, stream>>>(
            xb, xb + (size_t)CNT * KDIM, rowpart, colpart, pos);
        finalize1_kernel<<<dim3(32), dim3(256), 0, stream>>>(
            rowpart, colpart, pos, psum);
        finalize2_kernel<<<dim3(1), dim3(64), 0, stream>>>(psum, out);
    } else {
        unsigned* rowmin = (unsigned*)d_ws;
        unsigned* colmin = rowmin + CNT;
        float*    pos    = (float*)(colmin + CNT);
        init_min_kernel<<<dim3(2 * CNT / 256), dim3(256), 0, stream>>>(rowmin, 2 * CNT);
        dist_tile_kernel<<<dim3(CNT / BN, CNT / BM), dim3(256), 0, stream>>>(
            x, x + (size_t)CNT * KDIM, rowmin, colmin, pos);
        finalize_kernel<<<dim3(1), dim3(1024), 0, stream>>>(rowmin, colmin, pos, out);
    }
}

// Round 9
// 92.830 us; speedup vs baseline: 2.0967x; 1.3879x over previous
//
#include <hip/hip_runtime.h>
#include <hip/hip_fp8.h>

// HardNetLoss: a = x[:8192], p = x[8192:], d_ij = sqrt((1 - a_i·p_j + 1e-6)*2)
// pos_i = d_ii ; neg_i = min(min_{j!=i} d_ji, min_{j!=i} d_ij)
// out = mean(relu(1 - neg + pos))
//
// R19 (final): revert to R12 verbatim -- the best measured total (91.76us).
// Session findings (R10-R18): the dist kernel is latency-floor-bound at
// ~31us across ALL of {dup-feed, LDS-feed} x {global atomics, plain
// coalesced partials} x {2048/512/4096/1024-block, 2/4-per-CU, 16-wave}
// structures; no pipe ever exceeded ~30% busy (Mfma<=12, VALU<=30,
// HBM<=30). The remaining ~58us of the timed region is the harness's
// 256MB ws poison fill (43.5us @ 78% HBM, itself at roofline) + restore/
// launch plumbing. Known-bad moves, with counters: fused last-block
// finalize (device fence + same-address atomics, +120us, R13); per-kc
// drain barriers with only 4 K-steps (+3us, R11); single-lane scattered
// stores (WRITE 158MB, R16); 16-wave mega-blocks (whole-CU barrier
// drains, R18).
// 32x32 C/D layout: col = lane&31, row = (reg&3)+8*(reg>>2)+4*(lane>>5).

#define CNT    8192
#define KDIM   256
#define BIGF   3.0e38f
#define SCALE1 0x7F7F7F7F            // 4x e8m0 bytes, each = 2^0

typedef float f32x4  __attribute__((ext_vector_type(4)));
typedef float f32x16 __attribute__((ext_vector_type(16)));
typedef int   v8i    __attribute__((ext_vector_type(8)));

union frag8 { uint4 q[2]; v8i v; };

__device__ __forceinline__ unsigned short f2bf(float f) {
    unsigned u = __float_as_uint(f);
    u += 0x7FFFu + ((u >> 16) & 1u);          // round-to-nearest-even
    return (unsigned short)(u >> 16);
}

__device__ __forceinline__ unsigned cvt4_fp8(float a, float b, float c, float d) {
#if __has_builtin(__builtin_amdgcn_cvt_pk_fp8_f32)
    unsigned v = __builtin_amdgcn_cvt_pk_fp8_f32(a, b, 0, false);
    v = __builtin_amdgcn_cvt_pk_fp8_f32(c, d, v, true);
    return v;
#else
    return (unsigned)__hip_fp8_e4m3(a).__x |
           ((unsigned)__hip_fp8_e4m3(b).__x << 8) |
           ((unsigned)__hip_fp8_e4m3(c).__x << 16) |
           ((unsigned)__hip_fp8_e4m3(d).__x << 24);
#endif
}

// ---------------- fast path ----------------

// x fp32 [16384][256] -> xb fp8, MX-fragment-packed. Chunk (rg32, kc64) is
// 2KB: half h holds j 0..15 (h=0) / 16..31 (h=1) of each lane's 32-k block;
// lane = (row%32) + 32*((col%64)/32). Thread T writes 16B at xb + T*16.
__global__ __launch_bounds__(256) void convert_mx_kernel(
    const float* __restrict__ x, unsigned char* __restrict__ xb,
    unsigned* __restrict__ mins)
{
    int T    = blockIdx.x * 256 + threadIdx.x;   // 262144 threads
    int lane = T & 63;
    int h    = (T >> 6) & 1;
    int c    = T >> 7;                           // chunk 0..2047
    int kc64 = c & 3;
    int rg   = c >> 2;                           // 32-row group
    int row  = rg * 32 + (lane & 31);
    int col0 = kc64 * 64 + (lane >> 5) * 32 + h * 16;
    const float* src = x + (size_t)row * KDIM + col0;
    float4 u0 = *(const float4*)(src);
    float4 u1 = *(const float4*)(src + 4);
    float4 u2 = *(const float4*)(src + 8);
    float4 u3 = *(const float4*)(src + 12);
    uint4 w;
    w.x = cvt4_fp8(u0.x, u0.y, u0.z, u0.w);
    w.y = cvt4_fp8(u1.x, u1.y, u1.z, u1.w);
    w.z = cvt4_fp8(u2.x, u2.y, u2.z, u2.w);
    w.w = cvt4_fp8(u3.x, u3.y, u3.z, u3.w);
    *(uint4*)(xb + (size_t)T * 16) = w;
    if (T < 2 * CNT) mins[T] = 0x7F7FFFFFu;      // FLT_MAX bits
}

// Stage ALL of the block's P rows (8 rg x 4 kc = 32 chunks x 2KB = 64KB)
// into LDS. LDS layout: chunk cc = kc*8 + rg at cc*2048 (+h*1024), i.e.
// exactly the packed global layout reordered so kc is the outer index.
// Each wave issues 16 global_load_lds_dwordx4; dest is wave-uniform base,
// HW adds lane*16 -- matching the packed fragment layout.
__device__ __forceinline__ void stage_P(
    const char* __restrict__ Pb, char* lbuf, int bn, int wave, int lane)
{
    #pragma unroll
    for (int t = 0; t < 16; t++) {
        const int o   = wave * 16 + t;           // 0..63 half-chunks
        const int cc  = o >> 1;                  // 0..31 : kc*8 + rg
        const int h   = o & 1;
        const int rg  = cc & 7;
        const int kcs = cc >> 3;
        const char* src = Pb + (((size_t)(bn * 8 + rg)) << 13)
                             + kcs * 2048 + h * 1024 + lane * 16;
        __builtin_amdgcn_global_load_lds(
            (const __attribute__((address_space(1))) void*)src,
            (__attribute__((address_space(3))) void*)(lbuf + cc * 2048 + h * 1024),
            16, 0, 0);
    }
}

// block tile 128(m) x 256(n); 4 waves 2x2; wave tile 64x128 of 32x32x64 MFMA.
#define TST  136                                 // T leading stride (f32)
__global__ __launch_bounds__(256, 2) void dist12_kernel(
    const unsigned char* __restrict__ Ab_, const unsigned char* __restrict__ Pb_,
    unsigned* __restrict__ g_rowmin, unsigned* __restrict__ g_colmin,
    float* __restrict__ g_pos)
{
    __shared__ char smem[65536];                 // P staging; epilogue T aliases

    const char* Ab = (const char*)Ab_;
    const char* Pb = (const char*)Pb_;

    const int tid  = threadIdx.x;
    // XCD-aware swizzle: 8 regions of 16x16 blocks
    const int l    = blockIdx.x;
    const int xcd  = l & 7;
    const int i    = l >> 3;                     // 0..255
    const int bm   = (xcd >> 1) * 16 + (i & 15); // 0..63
    const int bn   = (xcd & 1) * 16 + (i >> 4);  // 0..31

    const int wave = tid >> 6;
    const int lane = tid & 63;
    const int l31  = lane & 31;
    const int kh   = lane >> 5;                  // k-half / C-row-half selector
    const int wm   = wave >> 1;                  // 0..1 : m half
    const int wn   = wave & 1;                   // 0..1 : n half

    // prologue: DMA all of P into LDS. The single mandatory sync: the
    // compiler cannot see the DMA->LDS dependence, and __syncthreads'
    // full drain (vmcnt 0 before s_barrier) is exactly what's needed.
    stage_P(Pb, smem, bn, wave, lane);
    __syncthreads();

    f32x16 acc[2][4];
    #pragma unroll
    for (int a = 0; a < 2; a++)
        #pragma unroll
        for (int b = 0; b < 4; b++)
            #pragma unroll
            for (int r = 0; r < 16; r++)
                acc[a][b][r] = 0.f;

    const char* Abase = Ab + lane * 16;
    size_t a_off[2];
    #pragma unroll
    for (int mi = 0; mi < 2; mi++)
        a_off[mi] = (size_t)(bm * 4 + wm * 2 + mi) << 13;    // rg32 * 8192

    // K-loop: 4 steps of K=64, NO barriers. A: depth-1 register prefetch
    // from global (compiler schedules vmcnt). B: ds_read_b128 from LDS
    // (lane-linear within 1KB halves -> conflict-free).
    frag8 ca[2], na[2];
    #pragma unroll
    for (int mi = 0; mi < 2; mi++) {
        ca[mi].q[0] = *(const uint4*)(Abase + a_off[mi]);
        ca[mi].q[1] = *(const uint4*)(Abase + a_off[mi] + 1024);
    }
    #pragma unroll
    for (int kc = 0; kc < 4; kc++) {
        if (kc < 3) {
            #pragma unroll
            for (int mi = 0; mi < 2; mi++) {
                na[mi].q[0] = *(const uint4*)(Abase + a_off[mi] + (kc + 1) * 2048);
                na[mi].q[1] = *(const uint4*)(Abase + a_off[mi] + (kc + 1) * 2048 + 1024);
            }
        }
        frag8 fb[4];
        #pragma unroll
        for (int ni = 0; ni < 4; ni++) {
            const char* p = smem + (kc * 8 + wn * 4 + ni) * 2048 + lane * 16;
            fb[ni].q[0] = *(const uint4*)(p);
            fb[ni].q[1] = *(const uint4*)(p + 1024);
        }
        #pragma unroll
        for (int mi = 0; mi < 2; mi++)
            #pragma unroll
            for (int ni = 0; ni < 4; ni++)
                acc[mi][ni] = __builtin_amdgcn_mfma_scale_f32_32x32x64_f8f6f4(
                    ca[mi].v, fb[ni].v, acc[mi][ni],
                    0, 0,                 // cbsz = fp8 e4m3, blgp = fp8 e4m3
                    0, SCALE1,            // scale_a opsel, scale_a
                    0, SCALE1);           // scale_b opsel, scale_b
        if (kc < 3) {
            #pragma unroll
            for (int mi = 0; mi < 2; mi++) ca[mi] = na[mi];
        }
    }

    // ---- epilogue. C/D: col = l31, row = (reg&3) + 8*(reg>>2) + 4*kh.
    // local row rl = wm*64 + mi*32 + rowf(reg)   (0..127)
    // local col cl = wn*128 + ni*32 + l31        (0..255)

    if ((bm >> 1) == bn) {                       // diagonal band
        const int dstart = (bm & 1) * 128;
        #pragma unroll
        for (int mi = 0; mi < 2; mi++)
            #pragma unroll
            for (int ni = 0; ni < 4; ni++)
                #pragma unroll
                for (int reg = 0; reg < 16; reg++) {
                    int rl = wm * 64 + mi * 32 + (reg & 3) + 8 * (reg >> 2) + 4 * kh;
                    int cl = wn * 128 + ni * 32 + l31;
                    if (cl == rl + dstart) {
                        g_pos[bm * 128 + rl] = (1.0f - acc[mi][ni][reg] + 1e-6f) * 2.0f;
                        acc[mi][ni][reg] = -BIGF;
                    }
                }
    }

    // col-direction (min over rows => max s): in-lane fold + 1 shuffle (kh)
    #pragma unroll
    for (int ni = 0; ni < 4; ni++) {
        float v = -BIGF;
        #pragma unroll
        for (int mi = 0; mi < 2; mi++)
            #pragma unroll
            for (int reg = 0; reg < 16; reg++)
                v = fmaxf(v, acc[mi][ni][reg]);
        v = fmaxf(v, __shfl_xor(v, 32, 64));
        if (kh == 0) {
            float tt = fmaxf((1.0f - v + 1e-6f) * 2.0f, 0.0f);
            atomicMin(&g_colmin[bn * 256 + wn * 128 + ni * 32 + l31],
                      __float_as_uint(tt));
        }
    }

    // row-direction: fold over ni in-lane; rows come in reg&3-contiguous runs
    // of 4 -> f32x4 LDS transpose writes; waves write disjoint (entry,row).
    // T aliases the P staging buffer -- full barrier first (all P reads done).
    __syncthreads();
    float* T = (float*)smem;                     // 64*TST*4 = 34816 <= 65536
    const int entry = wn * 32 + l31;             // 0..63
    #pragma unroll
    for (int mi = 0; mi < 2; mi++)
        #pragma unroll
        for (int q = 0; q < 4; q++) {
            f32x4 v;
            #pragma unroll
            for (int rr = 0; rr < 4; rr++) {
                float m = acc[mi][0][q * 4 + rr];
                #pragma unroll
                for (int ni = 1; ni < 4; ni++)
                    m = fmaxf(m, acc[mi][ni][q * 4 + rr]);
                v[rr] = m;
            }
            *(f32x4*)&T[entry * TST + wm * 64 + mi * 32 + q * 8 + kh * 4] = v;
        }
    __syncthreads();

    if (tid < 128) {
        int row = tid;
        float v0 = T[row], v1 = T[TST + row];
        #pragma unroll
        for (int e = 2; e < 64; e += 2) {
            v0 = fmaxf(v0, T[e * TST + row]);
            v1 = fmaxf(v1, T[(e + 1) * TST + row]);
        }
        float v = fmaxf(v0, v1);
        float tt = fmaxf((1.0f - v + 1e-6f) * 2.0f, 0.0f);
        atomicMin(&g_rowmin[bm * 128 + row], __float_as_uint(tt));
    }
}

__global__ __launch_bounds__(1024) void finalize_t_kernel(
    const unsigned* __restrict__ rm, const unsigned* __restrict__ cm,
    const float* __restrict__ post, float* __restrict__ out)
{
    float local = 0.f;
    for (int i = threadIdx.x; i < CNT; i += 1024) {
        float t   = fminf(__uint_as_float(rm[i]), __uint_as_float(cm[i]));
        float neg = sqrtf(fmaxf(t, 0.f));
        float pos = sqrtf(fmaxf(post[i], 0.f));
        local += fmaxf(1.0f - neg + pos, 0.0f);
    }
    #pragma unroll
    for (int m = 1; m < 64; m <<= 1) local += __shfl_xor(local, m, 64);
    __shared__ float wsum[16];
    if ((threadIdx.x & 63) == 0) wsum[threadIdx.x >> 6] = local;
    __syncthreads();
    if (threadIdx.x == 0) {
        float s = 0.f;
        #pragma unroll
        for (int w = 0; w < 16; w++) s += wsum[w];
        out[0] = s * (1.0f / (float)CNT);
    }
}

// ---------------- fallback path (round-1, known passing; 96 KB ws) ----------------

#define BM 128
#define BN 128
#define BK 64
#define KST (BK + 8)

typedef __bf16 bf16x8 __attribute__((ext_vector_type(8)));

__global__ __launch_bounds__(256) void init_min_kernel(unsigned* buf, int n) {
    int i = blockIdx.x * 256 + threadIdx.x;
    if (i < n) buf[i] = 0x7F7FFFFFu;
}

__global__ __launch_bounds__(256) void dist_tile_kernel(
    const float* __restrict__ A, const float* __restrict__ P,
    unsigned* __restrict__ g_rowmin, unsigned* __restrict__ g_colmin,
    float* __restrict__ g_pos)
{
    __shared__ unsigned short As[BM * KST];
    __shared__ unsigned short Bs[BN * KST];
    __shared__ unsigned redrow[BM];
    __shared__ unsigned redcol[BN];

    const int tid  = threadIdx.x;
    const int bm   = blockIdx.y;
    const int bn   = blockIdx.x;
    const int wave = tid >> 6;
    const int lane = tid & 63;
    const int quad = lane >> 4;
    const int l15  = lane & 15;
    const int m_off = (wave >> 1) * 64;
    const int n_off = (wave & 1) * 64;

    if (tid < BM) redrow[tid] = 0x7F7FFFFFu;
    if (tid < BN) redcol[tid] = 0x7F7FFFFFu;

    f32x4 acc[4][4];
    #pragma unroll
    for (int i = 0; i < 4; i++)
        #pragma unroll
        for (int j = 0; j < 4; j++)
            acc[i][j] = (f32x4){0.f, 0.f, 0.f, 0.f};

    const int srow = tid >> 4;
    const int scol = tid & 15;

    for (int kc = 0; kc < KDIM / BK; kc++) {
        #pragma unroll
        for (int i = 0; i < 8; i++) {
            int r = srow + i * 16;
            float4 va = *(const float4*)(A + (size_t)(bm * BM + r) * KDIM + kc * BK + scol * 4);
            float4 vb = *(const float4*)(P + (size_t)(bn * BN + r) * KDIM + kc * BK + scol * 4);
            ushort4 wa, wb;
            wa.x = f2bf(va.x); wa.y = f2bf(va.y); wa.z = f2bf(va.z); wa.w = f2bf(va.w);
            wb.x = f2bf(vb.x); wb.y = f2bf(vb.y); wb.z = f2bf(vb.z); wb.w = f2bf(vb.w);
            *(ushort4*)(&As[r * KST + scol * 4]) = wa;
            *(ushort4*)(&Bs[r * KST + scol * 4]) = wb;
        }
        __syncthreads();
        #pragma unroll
        for (int ks = 0; ks < BK / 32; ks++) {
            bf16x8 af[4], bfr[4];
            #pragma unroll
            for (int mi = 0; mi < 4; mi++)
                af[mi] = *(const bf16x8*)(&As[(m_off + mi * 16 + l15) * KST + ks * 32 + quad * 8]);
            #pragma unroll
            for (int ni = 0; ni < 4; ni++)
                bfr[ni] = *(const bf16x8*)(&Bs[(n_off + ni * 16 + l15) * KST + ks * 32 + quad * 8]);
            #pragma unroll
            for (int mi = 0; mi < 4; mi++)
                #pragma unroll
                for (int ni = 0; ni < 4; ni++)
                    acc[mi][ni] = __builtin_amdgcn_mfma_f32_16x16x32_bf16(
                        af[mi], bfr[ni], acc[mi][ni], 0, 0, 0);
        }
        __syncthreads();
    }

    float rmin[4][4], cmin[4];
    #pragma unroll
    for (int mi = 0; mi < 4; mi++)
        #pragma unroll
        for (int r = 0; r < 4; r++) rmin[mi][r] = BIGF;
    #pragma unroll
    for (int ni = 0; ni < 4; ni++) cmin[ni] = BIGF;

    const int grow0 = bm * BM + m_off + quad * 4;
    const int gcol0 = bn * BN + n_off + l15;

    #pragma unroll
    for (int mi = 0; mi < 4; mi++)
        #pragma unroll
        for (int ni = 0; ni < 4; ni++) {
            int gcol = gcol0 + ni * 16;
            #pragma unroll
            for (int r = 0; r < 4; r++) {
                int grow = grow0 + mi * 16 + r;
                float s = acc[mi][ni][r];
                float d = sqrtf((1.0f - s + 1e-6f) * 2.0f);
                float dm = d;
                if (grow == gcol) { g_pos[grow] = d; dm = BIGF; }
                rmin[mi][r] = fminf(rmin[mi][r], dm);
                cmin[ni]    = fminf(cmin[ni], dm);
            }
        }

    #pragma unroll
    for (int mi = 0; mi < 4; mi++)
        #pragma unroll
        for (int r = 0; r < 4; r++) {
            float v = rmin[mi][r];
            v = fminf(v, __shfl_xor(v, 1, 64));
            v = fminf(v, __shfl_xor(v, 2, 64));
            v = fminf(v, __shfl_xor(v, 4, 64));
            v = fminf(v, __shfl_xor(v, 8, 64));
            rmin[mi][r] = v;
        }
    #pragma unroll
    for (int ni = 0; ni < 4; ni++) {
        float v = cmin[ni];
        v = fminf(v, __shfl_xor(v, 16, 64));
        v = fminf(v, __shfl_xor(v, 32, 64));
        cmin[ni] = v;
    }

    if (l15 == 0) {
        #pragma unroll
        for (int mi = 0; mi < 4; mi++)
            #pragma unroll
            for (int r = 0; r < 4; r++)
                atomicMin(&redrow[m_off + mi * 16 + quad * 4 + r],
                          __float_as_uint(rmin[mi][r]));
    }
    if (quad == 0) {
        #pragma unroll
        for (int ni = 0; ni < 4; ni++)
            atomicMin(&redcol[n_off + ni * 16 + l15], __float_as_uint(cmin[ni]));
    }
    __syncthreads();

    if (tid < 128) atomicMin(&g_rowmin[bm * BM + tid], redrow[tid]);
    else           atomicMin(&g_colmin[bn * BN + (tid - 128)], redcol[tid - 128]);
}

__global__ __launch_bounds__(1024) void finalize_kernel(
    const unsigned* __restrict__ g_rowmin, const unsigned* __restrict__ g_colmin,
    const float* __restrict__ g_pos, float* __restrict__ out)
{
    float local = 0.f;
    for (int i = threadIdx.x; i < CNT; i += 1024) {
        float neg = fminf(__uint_as_float(g_rowmin[i]), __uint_as_float(g_colmin[i]));
        float v = 1.0f - neg + g_pos[i];
        local += fmaxf(v, 0.0f);
    }
    #pragma unroll
    for (int m = 1; m < 64; m <<= 1) local += __shfl_xor(local, m, 64);
    __shared__ float wsum[16];
    if ((threadIdx.x & 63) == 0) wsum[threadIdx.x >> 6] = local;
    __syncthreads();
    if (threadIdx.x == 0) {
        float s = 0.f;
        #pragma unroll
        for (int w = 0; w < 16; w++) s += wsum[w];
        out[0] = s * (1.0f / (float)CNT);
    }
}

// ---------------- host ----------------

extern "C" void kernel_launch(void* const* d_in, const int* in_sizes, int n_in,
                              void* d_out, int out_size, void* d_ws, size_t ws_size,
                              hipStream_t stream) {
    const float* x = (const float*)d_in[0];
    float* out = (float*)d_out;

    const size_t fp8_bytes = (size_t)2 * CNT * KDIM;        // 4,194,304
    const size_t need = fp8_bytes + (size_t)2 * CNT * 4 + (size_t)CNT * 4;

    if (ws_size >= need) {
        unsigned char* xb   = (unsigned char*)d_ws;
        unsigned*      mins = (unsigned*)((char*)d_ws + fp8_bytes);
        float*         pos  = (float*)(mins + 2 * CNT);
        convert_mx_kernel<<<dim3(1024), dim3(256), 0, stream>>>(x, xb, mins);
        dist12_kernel<<<dim3(2048), dim3(256), 0, stream>>>(
            xb, xb + (size_t)CNT * KDIM, mins, mins + CNT, pos);
        finalize_t_kernel<<<dim3(1), dim3(1024), 0, stream>>>(mins, mins + CNT, pos, out);
    } else {
        unsigned* rowmin = (unsigned*)d_ws;
        unsigned* colmin = rowmin + CNT;
        float*    pos    = (float*)(colmin + CNT);
        init_min_kernel<<<dim3(2 * CNT / 256), dim3(256), 0, stream>>>(rowmin, 2 * CNT);
        dist_tile_kernel<<<dim3(CNT / BN, CNT / BM), dim3(256), 0, stream>>>(
            x, x + (size_t)CNT * KDIM, rowmin, colmin, pos);
        finalize_kernel<<<dim3(1), dim3(1024), 0, stream>>>(rowmin, colmin, pos, out);
    }
}